// Round 7
// baseline (395.656 us; speedup 1.0000x reference)
//
#include <hip/hip_runtime.h>
#include <hip/hip_fp16.h>

#define CIN   64
#define COUT  64

typedef __attribute__((ext_vector_type(8))) short bf16x8;
typedef __attribute__((ext_vector_type(4))) float f32x4;

// round-to-nearest-even f32 -> bf16 (bit pattern as ushort)
__device__ inline unsigned short f2bf(float f) {
    unsigned u = __float_as_uint(f);
    return (unsigned short)((u + 0x7FFFu + ((u >> 16) & 1u)) >> 16);
}

__device__ inline unsigned pack_h2(float lo, float hi) {
    __half l = __float2half(lo), h = __float2half(hi);
    return (unsigned)__half_as_ushort(l) | ((unsigned)__half_as_ushort(h) << 16);
}

// HW packed-fp16 atomic add: ONE 4B atomic sub-op covers 2 columns.
// ROCm 7 removed the __builtin_amdgcn_global_atomic_fadd_v2f16 builtin
// (round-6 lesson: __has_builtin guard silently took the fallback), so emit
// the gfx950 instruction directly.
__device__ inline void pk_add_f16(void* addr, unsigned data) {
    asm volatile("global_atomic_pk_add_f16 %0, %1, off"
                 :: "v"(addr), "v"(data)
                 : "memory");
}

// ---------------------------------------------------------------------------
// feats fp32 -> bf16 rows (one-time per launch; 51.2 MB read / 25.6 MB write)
// ---------------------------------------------------------------------------
__global__ __launch_bounds__(256)
void cvt_feats(const float4* __restrict__ in, unsigned short* __restrict__ outb,
               int n8) {
    int i = blockIdx.x * 256 + threadIdx.x;
    if (i >= n8) return;
    float4 f0 = in[2 * i], f1 = in[2 * i + 1];
    bf16x8 o;
    o[0] = (short)f2bf(f0.x); o[1] = (short)f2bf(f0.y);
    o[2] = (short)f2bf(f0.z); o[3] = (short)f2bf(f0.w);
    o[4] = (short)f2bf(f1.x); o[5] = (short)f2bf(f1.y);
    o[6] = (short)f2bf(f1.z); o[7] = (short)f2bf(f1.w);
    *(bf16x8*)(outb + 8 * (size_t)i) = o;
}

// ---------------------------------------------------------------------------
// fp16 accumulator -> fp32 out (every element written; no out-memset needed)
// ---------------------------------------------------------------------------
__global__ __launch_bounds__(256)
void cvt_out(const __half2* __restrict__ hacc, float2* __restrict__ out, int n2) {
    int i = blockIdx.x * 256 + threadIdx.x;
    if (i >= n2) return;
    const __half2 h = hacc[i];
    out[i] = make_float2(__half2float(__low2half(h)), __half2float(__high2half(h)));
}

// ---------------------------------------------------------------------------
// Single-phase implicit-GEMM with packed-fp16 atomic scatter.
// One wave = 16 pairs/iter via v_mfma_f32_16x16x32_bf16; W[k] in registers;
// A gathered from pre-converted bf16 feats (2x16B loads/lane, no cvt).
// Scatter: cols paired via shfl_xor(1) -> one global_atomic_pk_add_f16 per
// (row, col-pair): 43.2M 4B atomic sub-ops vs 86.4M for scalar f32.
// ---------------------------------------------------------------------------
__global__ __launch_bounds__(256)
void spconv_pk(const unsigned short* __restrict__ featsb,
               const float*          __restrict__ weight,
               const int*            __restrict__ in_map,
               const int*            __restrict__ out_map,
               __half*               __restrict__ hacc,
               int M) {
    const int k      = blockIdx.y;
    const int tid    = threadIdx.x;
    const int lane   = tid & 63;
    const int m      = lane & 15;
    const int quad   = lane >> 4;
    const int wave   = blockIdx.x * 4 + (tid >> 6);
    const int nwaves = gridDim.x * 4;
    const bool odd   = (m & 1);

    // Preload B fragments: b[t][h][j] = W[k][32h+8q+j][16t+m]
    const float* __restrict__ wk = weight + (size_t)k * (CIN * COUT);
    bf16x8 bfrag[4][2];
#pragma unroll
    for (int t = 0; t < 4; ++t)
#pragma unroll
        for (int h = 0; h < 2; ++h) {
            const int n  = 16 * t + m;
            const int c0 = 32 * h + 8 * quad;
#pragma unroll
            for (int j = 0; j < 8; ++j)
                bfrag[t][h][j] = (short)f2bf(wk[(c0 + j) * COUT + n]);
        }

    const int base   = k * M;
    const int ntiles = M >> 4;   // 3125

    unsigned* const hacc2 = (unsigned*)hacc;   // dword-indexed (2 cols / dword)

    for (int tile = wave; tile < ntiles; tile += nwaves) {
        const int p0      = tile << 4;
        const int in_row  = in_map[base + p0 + m];
        const int out_row = out_map[base + p0 + m];

        const unsigned short* fb = featsb + ((size_t)in_row << 6) + 8 * quad;
        const bf16x8 a0 = *(const bf16x8*)fb;          // channels [8q, 8q+8)
        const bf16x8 a1 = *(const bf16x8*)(fb + 32);   // channels [8q+32, 8q+40)

        int orow[4];
#pragma unroll
        for (int r = 0; r < 4; ++r)
            orow[r] = __shfl(out_row, 4 * quad + r);

        f32x4 acc[4];
#pragma unroll
        for (int t = 0; t < 4; ++t) {
            acc[t] = {0.f, 0.f, 0.f, 0.f};
            acc[t] = __builtin_amdgcn_mfma_f32_16x16x32_bf16(a0, bfrag[t][0], acc[t], 0, 0, 0);
            acc[t] = __builtin_amdgcn_mfma_f32_16x16x32_bf16(a1, bfrag[t][1], acc[t], 0, 0, 0);
        }

        // Pair cols (m, m^1) via shfl_xor(1): even lane takes C-rows 4q+{0,1},
        // odd lane rows 4q+{2,3}; one pk_add_f16 per (row, colpair).
        const int coldw = m >> 1;                 // + 8t per tile below
        const int ra = odd ? orow[2] : orow[0];
        const int rb = odd ? orow[3] : orow[1];
#pragma unroll
        for (int t = 0; t < 4; ++t) {
            const float send0 = odd ? acc[t][0] : acc[t][2];
            const float send1 = odd ? acc[t][1] : acc[t][3];
            const float recv0 = __shfl_xor(send0, 1);
            const float recv1 = __shfl_xor(send1, 1);

            const unsigned da = odd ? pack_h2(recv0, acc[t][2])
                                    : pack_h2(acc[t][0], recv0);
            const unsigned db = odd ? pack_h2(recv1, acc[t][3])
                                    : pack_h2(acc[t][1], recv1);

            pk_add_f16(&hacc2[(size_t)ra * 32 + coldw + 8 * t], da);
            pk_add_f16(&hacc2[(size_t)rb * 32 + coldw + 8 * t], db);
        }
    }
}

// ---------------------------------------------------------------------------
// Fallback (ws too small): round-2 kernel — scalar f32 atomics (known-good).
// ---------------------------------------------------------------------------
__global__ __launch_bounds__(256)
void spconv_atomic(const float* __restrict__ feats,
                   const float* __restrict__ weight,
                   const int*   __restrict__ in_map,
                   const int*   __restrict__ out_map,
                   float*       __restrict__ out,
                   int M) {
    const int k      = blockIdx.y;
    const int tid    = threadIdx.x;
    const int lane   = tid & 63;
    const int m      = lane & 15;
    const int quad   = lane >> 4;
    const int wave   = blockIdx.x * 4 + (tid >> 6);
    const int nwaves = gridDim.x * 4;

    const float* __restrict__ wk = weight + (size_t)k * (CIN * COUT);
    bf16x8 bfrag[4][2];
#pragma unroll
    for (int t = 0; t < 4; ++t)
#pragma unroll
        for (int h = 0; h < 2; ++h) {
            const int n  = 16 * t + m;
            const int c0 = 32 * h + 8 * quad;
#pragma unroll
            for (int j = 0; j < 8; ++j)
                bfrag[t][h][j] = (short)f2bf(wk[(c0 + j) * COUT + n]);
        }

    const int base   = k * M;
    const int ntiles = M >> 4;

    for (int tile = wave; tile < ntiles; tile += nwaves) {
        const int p0 = tile << 4;
        const int in_row  = in_map[base + p0 + m];
        const int out_row = out_map[base + p0 + m];

        const float* __restrict__ fr = feats + ((size_t)in_row << 6) + 8 * quad;
        const f32x4 f0 = *(const f32x4*)(fr + 0);
        const f32x4 f1 = *(const f32x4*)(fr + 4);
        const f32x4 f2 = *(const f32x4*)(fr + 32);
        const f32x4 f3 = *(const f32x4*)(fr + 36);

        bf16x8 a0, a1;
#pragma unroll
        for (int j = 0; j < 4; ++j) {
            a0[j]     = (short)f2bf(f0[j]);
            a0[j + 4] = (short)f2bf(f1[j]);
            a1[j]     = (short)f2bf(f2[j]);
            a1[j + 4] = (short)f2bf(f3[j]);
        }

        int orow[4];
#pragma unroll
        for (int r = 0; r < 4; ++r)
            orow[r] = __shfl(out_row, 4 * quad + r);

        f32x4 acc[4];
#pragma unroll
        for (int t = 0; t < 4; ++t) {
            acc[t] = {0.f, 0.f, 0.f, 0.f};
            acc[t] = __builtin_amdgcn_mfma_f32_16x16x32_bf16(a0, bfrag[t][0], acc[t], 0, 0, 0);
            acc[t] = __builtin_amdgcn_mfma_f32_16x16x32_bf16(a1, bfrag[t][1], acc[t], 0, 0, 0);
        }

#pragma unroll
        for (int t = 0; t < 4; ++t)
#pragma unroll
            for (int r = 0; r < 4; ++r)
                atomicAdd(out + (size_t)orow[r] * COUT + 16 * t + m, acc[t][r]);
    }
}

__global__ __launch_bounds__(256)
void zero_out_kernel(float4* __restrict__ out, int n4) {
    int i = blockIdx.x * 256 + threadIdx.x;
    if (i < n4) out[i] = make_float4(0.f, 0.f, 0.f, 0.f);
}

extern "C" void kernel_launch(void* const* d_in, const int* in_sizes, int n_in,
                              void* d_out, int out_size, void* d_ws, size_t ws_size,
                              hipStream_t stream) {
    const float* feats   = (const float*)d_in[0];
    const float* weight  = (const float*)d_in[1];
    const int*   in_map  = (const int*)d_in[2];
    const int*   out_map = (const int*)d_in[3];
    float*       out     = (float*)d_out;

    const int K = in_sizes[1] / (CIN * COUT);   // 27
    const int M = in_sizes[2] / K;              // 50000
    const int N = out_size / COUT;              // 200000

    // ws layout: featsb bf16[N*CIN] | hacc fp16[N*COUT]
    const size_t fb_b   = ((size_t)N * CIN * 2 + 255) & ~(size_t)255;
    const size_t hacc_b = (size_t)N * COUT * 2;
    const size_t need   = fb_b + hacc_b;

    if ((M & 15) == 0 && ws_size >= need) {
        unsigned short* featsb = (unsigned short*)d_ws;
        __half*         hacc   = (__half*)((char*)d_ws + fb_b);

        hipMemsetAsync(hacc, 0, hacc_b, stream);          // fp16 0.0 == 0x0000

        const int n8 = N * CIN / 8;
        cvt_feats<<<(n8 + 255) / 256, 256, 0, stream>>>(
            (const float4*)feats, featsb, n8);

        dim3 grid(80, K);
        spconv_pk<<<grid, 256, 0, stream>>>(featsb, weight, in_map, out_map,
                                            hacc, M);

        const int n2 = N * COUT / 2;
        cvt_out<<<(n2 + 255) / 256, 256, 0, stream>>>(
            (const __half2*)hacc, (float2*)out, n2);
        return;
    }

    // Fallback: known-good scalar-atomic path.
    int n4 = out_size / 4;
    zero_out_kernel<<<(n4 + 255) / 256, 256, 0, stream>>>((float4*)out, n4);
    dim3 grid(80, K);
    spconv_atomic<<<grid, 256, 0, stream>>>(feats, weight, in_map, out_map, out, M);
}

// Round 8
// 363.790 us; speedup vs baseline: 1.0876x; 1.0876x over previous
//
#include <hip/hip_runtime.h>
#include <hip/hip_fp16.h>

#define CIN   64
#define COUT  64

typedef __attribute__((ext_vector_type(8))) short bf16x8;
typedef __attribute__((ext_vector_type(4))) float f32x4;

// round-to-nearest-even f32 -> bf16 (bit pattern as ushort)
__device__ inline unsigned short f2bf(float f) {
    unsigned u = __float_as_uint(f);
    return (unsigned short)((u + 0x7FFFu + ((u >> 16) & 1u)) >> 16);
}

__device__ inline unsigned pack_h2(float lo, float hi) {
    __half l = __float2half(lo), h = __float2half(hi);
    return (unsigned)__half_as_ushort(l) | ((unsigned)__half_as_ushort(h) << 16);
}

// ---------------------------------------------------------------------------
// CSR build step 1: histogram of out_map into cnt[] (800 KB, L2-resident
// atomics -- the ONLY random traffic in the whole build).
// ---------------------------------------------------------------------------
__global__ __launch_bounds__(256)
void hist_kernel(const int* __restrict__ out_map, int total, int* __restrict__ cnt) {
    int g = blockIdx.x * 256 + threadIdx.x;
    if (g >= total) return;
    atomicAdd(&cnt[out_map[g]], 1);
}

// CSR build step 2a: per-block (1024 elems) exclusive scan + block sums.
__global__ __launch_bounds__(256)
void scanA(const int* __restrict__ cnt, int* __restrict__ excl,
           int* __restrict__ blocksum, int N) {
    __shared__ int sm[256];
    const int b = blockIdx.x, t = threadIdx.x;
    const int base = b * 1024 + t * 4;
    int v0 = (base + 0 < N) ? cnt[base + 0] : 0;
    int v1 = (base + 1 < N) ? cnt[base + 1] : 0;
    int v2 = (base + 2 < N) ? cnt[base + 2] : 0;
    int v3 = (base + 3 < N) ? cnt[base + 3] : 0;
    const int s = v0 + v1 + v2 + v3;
    sm[t] = s; __syncthreads();
    for (int off = 1; off < 256; off <<= 1) {
        int x = (t >= off) ? sm[t - off] : 0;
        __syncthreads();
        sm[t] += x;
        __syncthreads();
    }
    const int e = sm[t] - s;
    if (t == 255) blocksum[b] = sm[t];
    if (base + 0 < N) excl[base + 0] = e;
    if (base + 1 < N) excl[base + 1] = e + v0;
    if (base + 2 < N) excl[base + 2] = e + v0 + v1;
    if (base + 3 < N) excl[base + 3] = e + v0 + v1 + v2;
}

// CSR build step 2b: scan the block sums (nb <= 256), write grand total.
__global__ __launch_bounds__(256)
void scanB(const int* __restrict__ blocksum, int* __restrict__ blockbase,
           int nb, int* __restrict__ total_out) {
    __shared__ int sm[256];
    const int t = threadIdx.x;
    const int s = (t < nb) ? blocksum[t] : 0;
    sm[t] = s; __syncthreads();
    for (int off = 1; off < 256; off <<= 1) {
        int x = (t >= off) ? sm[t - off] : 0;
        __syncthreads();
        sm[t] += x;
        __syncthreads();
    }
    if (t < nb) blockbase[t] = sm[t] - s;
    if (t == 255) *total_out = sm[255];
}

// CSR build step 2c: add block bases; duplicate into ofs_work for the fill.
__global__ __launch_bounds__(256)
void scanC(int* __restrict__ offsets, int* __restrict__ ofs_work,
           const int* __restrict__ blockbase, int N) {
    int i = blockIdx.x * 256 + threadIdx.x;
    if (i >= N) return;
    const int v = offsets[i] + blockbase[i >> 10];
    offsets[i]  = v;
    ofs_work[i] = v;
}

// CSR build step 3: slot[g] = CSR position (sequential write; atomics on the
// 800 KB L2-resident ofs_work only).
__global__ __launch_bounds__(256)
void fill_kernel(const int* __restrict__ out_map, int total,
                 int* __restrict__ ofs_work, int* __restrict__ slot) {
    int g = blockIdx.x * 256 + threadIdx.x;
    if (g >= total) return;
    slot[g] = atomicAdd(&ofs_work[out_map[g]], 1);
}

// ---------------------------------------------------------------------------
// feats fp32 -> bf16 rows (one-time per launch)
// ---------------------------------------------------------------------------
__global__ __launch_bounds__(256)
void cvt_feats(const float4* __restrict__ in, unsigned short* __restrict__ outb,
               int n8) {
    int i = blockIdx.x * 256 + threadIdx.x;
    if (i >= n8) return;
    float4 f0 = in[2 * i], f1 = in[2 * i + 1];
    bf16x8 o;
    o[0] = (short)f2bf(f0.x); o[1] = (short)f2bf(f0.y);
    o[2] = (short)f2bf(f0.z); o[3] = (short)f2bf(f0.w);
    o[4] = (short)f2bf(f1.x); o[5] = (short)f2bf(f1.y);
    o[6] = (short)f2bf(f1.z); o[7] = (short)f2bf(f1.w);
    *(bf16x8*)(outb + 8 * (size_t)i) = o;
}

// ---------------------------------------------------------------------------
// Phase 1: implicit-GEMM (MFMA); partial row for pair g written as fp16
// (32 dwords = 128 B) directly at CSR slot[g] -- phase 2 reads contiguously.
// ---------------------------------------------------------------------------
__global__ __launch_bounds__(256)
void spconv_phase1(const unsigned short* __restrict__ featsb,
                   const float*          __restrict__ weight,
                   const int*            __restrict__ in_map,
                   const int*            __restrict__ slot,
                   unsigned*             __restrict__ partial_dw,
                   int M) {
    const int k      = blockIdx.y;
    const int tid    = threadIdx.x;
    const int lane   = tid & 63;
    const int m      = lane & 15;
    const int quad   = lane >> 4;
    const int wave   = blockIdx.x * 4 + (tid >> 6);
    const int nwaves = gridDim.x * 4;
    const bool odd   = (m & 1);

    // Preload B fragments: b[t][h][j] = W[k][32h+8q+j][16t+m]
    const float* __restrict__ wk = weight + (size_t)k * (CIN * COUT);
    bf16x8 bfrag[4][2];
#pragma unroll
    for (int t = 0; t < 4; ++t)
#pragma unroll
        for (int h = 0; h < 2; ++h) {
            const int n  = 16 * t + m;
            const int c0 = 32 * h + 8 * quad;
#pragma unroll
            for (int j = 0; j < 8; ++j)
                bfrag[t][h][j] = (short)f2bf(wk[(c0 + j) * COUT + n]);
        }

    const int base   = k * M;
    const int ntiles = M >> 4;   // 3125

    for (int tile = wave; tile < ntiles; tile += nwaves) {
        const int p0     = tile << 4;
        const int in_row = in_map[base + p0 + m];
        const int slt    = slot[base + p0 + m];   // CSR slot of pair m

        const unsigned short* fb = featsb + ((size_t)in_row << 6) + 8 * quad;
        const bf16x8 a0 = *(const bf16x8*)fb;          // channels [8q, 8q+8)
        const bf16x8 a1 = *(const bf16x8*)(fb + 32);   // channels [8q+32, 8q+40)

        f32x4 acc[4];
#pragma unroll
        for (int t = 0; t < 4; ++t) {
            acc[t] = {0.f, 0.f, 0.f, 0.f};
            acc[t] = __builtin_amdgcn_mfma_f32_16x16x32_bf16(a0, bfrag[t][0], acc[t], 0, 0, 0);
            acc[t] = __builtin_amdgcn_mfma_f32_16x16x32_bf16(a1, bfrag[t][1], acc[t], 0, 0, 0);
        }

        // Epilogue: pair cols (m, m^1) via shfl_xor(1); even lane writes
        // C-rows 4q+{0,1}, odd lane 4q+{2,3}; dword half2 stores into the
        // destination rows' CSR slots.
        const int row0  = 4 * quad + (odd ? 2 : 0);
        const int s0    = __shfl(slt, row0);       // lane row0 holds m=row0
        const int s1    = __shfl(slt, row0 + 1);
        const int coldw = m >> 1;
#pragma unroll
        for (int t = 0; t < 4; ++t) {
            const float send0 = odd ? acc[t][0] : acc[t][2];
            const float send1 = odd ? acc[t][1] : acc[t][3];
            const float recv0 = __shfl_xor(send0, 1);
            const float recv1 = __shfl_xor(send1, 1);

            const unsigned d0 = odd ? pack_h2(recv0, acc[t][2])
                                    : pack_h2(acc[t][0], recv0);
            const unsigned d1 = odd ? pack_h2(recv1, acc[t][3])
                                    : pack_h2(acc[t][1], recv1);

            partial_dw[(size_t)s0 * 32 + coldw + 8 * t] = d0;
            partial_dw[(size_t)s1 * 32 + coldw + 8 * t] = d1;
        }
    }
}

// ---------------------------------------------------------------------------
// Phase 2: streaming CSR reduce. One wave per out row; contributions are
// CONTIGUOUS (slots [offsets[r], offsets[r+1])). Lane reads a dword (2 cols);
// 32 lanes cover one 128 B entry; 2 entries/step, 4 loads in flight.
// ---------------------------------------------------------------------------
__global__ __launch_bounds__(256)
void spconv_phase2(const unsigned* __restrict__ partial_dw,
                   const int*      __restrict__ offsets,
                   float2*         __restrict__ out,
                   int nrows) {
    const int tid  = threadIdx.x;
    const int lane = tid & 63;
    const int half = lane >> 5;
    const int c2   = lane & 31;
    const int wave = blockIdx.x * 4 + (tid >> 6);
    const int nw   = gridDim.x * 4;

    for (int r = wave; r < nrows; r += nw) {
        const int start = offsets[r];
        const int c     = offsets[r + 1] - start;

        float ax = 0.f, ay = 0.f;
        for (int j0 = 0; j0 < c; j0 += 8) {
#pragma unroll
            for (int u = 0; u < 4; ++u) {
                const int j = j0 + 2 * u + half;
                if (j < c) {
                    const unsigned v = partial_dw[(size_t)(start + j) * 32 + c2];
                    ax += __half2float(__ushort_as_half((unsigned short)(v & 0xFFFF)));
                    ay += __half2float(__ushort_as_half((unsigned short)(v >> 16)));
                }
            }
        }

        ax += __shfl_xor(ax, 32);
        ay += __shfl_xor(ay, 32);
        if (half == 0)
            out[(size_t)r * 32 + c2] = make_float2(ax, ay);
    }
}

// ---------------------------------------------------------------------------
// Fallback (ws too small): round-2 kernel — scalar f32 atomics (known-good).
// ---------------------------------------------------------------------------
__global__ __launch_bounds__(256)
void spconv_atomic(const float* __restrict__ feats,
                   const float* __restrict__ weight,
                   const int*   __restrict__ in_map,
                   const int*   __restrict__ out_map,
                   float*       __restrict__ out,
                   int M) {
    const int k      = blockIdx.y;
    const int tid    = threadIdx.x;
    const int lane   = tid & 63;
    const int m      = lane & 15;
    const int quad   = lane >> 4;
    const int wave   = blockIdx.x * 4 + (tid >> 6);
    const int nwaves = gridDim.x * 4;

    const float* __restrict__ wk = weight + (size_t)k * (CIN * COUT);
    bf16x8 bfrag[4][2];
#pragma unroll
    for (int t = 0; t < 4; ++t)
#pragma unroll
        for (int h = 0; h < 2; ++h) {
            const int n  = 16 * t + m;
            const int c0 = 32 * h + 8 * quad;
#pragma unroll
            for (int j = 0; j < 8; ++j)
                bfrag[t][h][j] = (short)f2bf(wk[(c0 + j) * COUT + n]);
        }

    const int base   = k * M;
    const int ntiles = M >> 4;

    for (int tile = wave; tile < ntiles; tile += nwaves) {
        const int p0 = tile << 4;
        const int in_row  = in_map[base + p0 + m];
        const int out_row = out_map[base + p0 + m];

        const float* __restrict__ fr = feats + ((size_t)in_row << 6) + 8 * quad;
        const f32x4 f0 = *(const f32x4*)(fr + 0);
        const f32x4 f1 = *(const f32x4*)(fr + 4);
        const f32x4 f2 = *(const f32x4*)(fr + 32);
        const f32x4 f3 = *(const f32x4*)(fr + 36);

        bf16x8 a0, a1;
#pragma unroll
        for (int j = 0; j < 4; ++j) {
            a0[j]     = (short)f2bf(f0[j]);
            a0[j + 4] = (short)f2bf(f1[j]);
            a1[j]     = (short)f2bf(f2[j]);
            a1[j + 4] = (short)f2bf(f3[j]);
        }

        int orow[4];
#pragma unroll
        for (int r = 0; r < 4; ++r)
            orow[r] = __shfl(out_row, 4 * quad + r);

        f32x4 acc[4];
#pragma unroll
        for (int t = 0; t < 4; ++t) {
            acc[t] = {0.f, 0.f, 0.f, 0.f};
            acc[t] = __builtin_amdgcn_mfma_f32_16x16x32_bf16(a0, bfrag[t][0], acc[t], 0, 0, 0);
            acc[t] = __builtin_amdgcn_mfma_f32_16x16x32_bf16(a1, bfrag[t][1], acc[t], 0, 0, 0);
        }

#pragma unroll
        for (int t = 0; t < 4; ++t)
#pragma unroll
            for (int r = 0; r < 4; ++r)
                atomicAdd(out + (size_t)orow[r] * COUT + 16 * t + m, acc[t][r]);
    }
}

__global__ __launch_bounds__(256)
void zero_out_kernel(float4* __restrict__ out, int n4) {
    int i = blockIdx.x * 256 + threadIdx.x;
    if (i < n4) out[i] = make_float4(0.f, 0.f, 0.f, 0.f);
}

static inline size_t al256(size_t x) { return (x + 255) & ~(size_t)255; }

extern "C" void kernel_launch(void* const* d_in, const int* in_sizes, int n_in,
                              void* d_out, int out_size, void* d_ws, size_t ws_size,
                              hipStream_t stream) {
    const float* feats   = (const float*)d_in[0];
    const float* weight  = (const float*)d_in[1];
    const int*   in_map  = (const int*)d_in[2];
    const int*   out_map = (const int*)d_in[3];
    float*       out     = (float*)d_out;

    const int K     = in_sizes[1] / (CIN * COUT);   // 27
    const int M     = in_sizes[2] / K;              // 50000
    const int N     = out_size / COUT;              // 200000
    const int total = K * M;                        // 1.35M
    const int nb    = (N + 1023) >> 10;             // scan blocks (196)

    // ws layout: offsets[N+1] | ofs_work[N] | blocksum[nb] | blockbase[nb]
    //            | slot[total] | featsb bf16[N*CIN] | partial fp16[total*64]
    const size_t off_b  = al256((size_t)(N + 1) * 4);
    const size_t work_b = al256((size_t)N * 4);
    const size_t bs_b   = al256((size_t)nb * 4);
    const size_t bb_b   = al256((size_t)nb * 4);
    const size_t slot_b = al256((size_t)total * 4);
    const size_t fb_b   = al256((size_t)N * CIN * 2);
    const size_t part_b = (size_t)total * COUT * 2;
    const size_t need   = off_b + work_b + bs_b + bb_b + slot_b + fb_b + part_b;

    if ((M & 15) == 0 && nb <= 256 && ws_size >= need) {
        char* p = (char*)d_ws;
        int*            offsets   = (int*)p;            p += off_b;
        int*            ofs_work  = (int*)p;            p += work_b;
        int*            blocksum  = (int*)p;            p += bs_b;
        int*            blockbase = (int*)p;            p += bb_b;
        int*            slot      = (int*)p;            p += slot_b;
        unsigned short* featsb    = (unsigned short*)p; p += fb_b;
        unsigned*       partial   = (unsigned*)p;

        // --- CSR build ---
        hipMemsetAsync(ofs_work, 0, (size_t)N * 4, stream);
        hist_kernel<<<(total + 255) / 256, 256, 0, stream>>>(out_map, total, ofs_work);
        scanA<<<nb, 256, 0, stream>>>(ofs_work, offsets, blocksum, N);
        scanB<<<1, 256, 0, stream>>>(blocksum, blockbase, nb, offsets + N);
        scanC<<<(N + 255) / 256, 256, 0, stream>>>(offsets, ofs_work, blockbase, N);
        fill_kernel<<<(total + 255) / 256, 256, 0, stream>>>(out_map, total, ofs_work, slot);

        // --- feats -> bf16 ---
        const int n8 = N * CIN / 8;
        cvt_feats<<<(n8 + 255) / 256, 256, 0, stream>>>((const float4*)feats, featsb, n8);

        // --- phase 1: GEMM into CSR-ordered fp16 partials ---
        dim3 g1(80, K);
        spconv_phase1<<<g1, 256, 0, stream>>>(featsb, weight, in_map, slot, partial, M);

        // --- phase 2: streaming segmented reduce -> out ---
        spconv_phase2<<<4096, 256, 0, stream>>>(partial, offsets, (float2*)out, N);
        return;
    }

    // Fallback: known-good scalar-atomic path.
    int n4 = out_size / 4;
    zero_out_kernel<<<(n4 + 255) / 256, 256, 0, stream>>>((float4*)out, n4);
    dim3 grid(80, K);
    spconv_atomic<<<grid, 256, 0, stream>>>(feats, weight, in_map, out_map, out, M);
}

// Round 9
// 331.772 us; speedup vs baseline: 1.1926x; 1.0965x over previous
//
#include <hip/hip_runtime.h>
#include <hip/hip_fp16.h>

#define CIN   64
#define COUT  64

typedef __attribute__((ext_vector_type(8))) short bf16x8;
typedef __attribute__((ext_vector_type(4))) float f32x4;

// round-to-nearest-even f32 -> bf16 (bit pattern as ushort)
__device__ inline unsigned short f2bf(float f) {
    unsigned u = __float_as_uint(f);
    return (unsigned short)((u + 0x7FFFu + ((u >> 16) & 1u)) >> 16);
}

__device__ inline unsigned pack_h2(float lo, float hi) {
    __half l = __float2half(lo), h = __float2half(hi);
    return (unsigned)__half_as_ushort(l) | ((unsigned)__half_as_ushort(h) << 16);
}

// ---------------------------------------------------------------------------
// Fused: feats fp32 -> bf16 AND out_map histogram (cnt must be pre-zeroed).
// Grid covers max(n8, total).
// ---------------------------------------------------------------------------
__global__ __launch_bounds__(256)
void cvt_hist(const float4* __restrict__ in, unsigned short* __restrict__ outb,
              int n8, const int* __restrict__ out_map, int total,
              int* __restrict__ cnt) {
    int i = blockIdx.x * 256 + threadIdx.x;
    if (i < n8) {
        float4 f0 = in[2 * i], f1 = in[2 * i + 1];
        bf16x8 o;
        o[0] = (short)f2bf(f0.x); o[1] = (short)f2bf(f0.y);
        o[2] = (short)f2bf(f0.z); o[3] = (short)f2bf(f0.w);
        o[4] = (short)f2bf(f1.x); o[5] = (short)f2bf(f1.y);
        o[6] = (short)f2bf(f1.z); o[7] = (short)f2bf(f1.w);
        *(bf16x8*)(outb + 8 * (size_t)i) = o;
    }
    if (i < total)
        atomicAdd(&cnt[out_map[i]], 1);
}

// CSR build 2a: per-block (1024 elems) exclusive scan + block sums.
__global__ __launch_bounds__(256)
void scanA(const int* __restrict__ cnt, int* __restrict__ excl,
           int* __restrict__ blocksum, int N) {
    __shared__ int sm[256];
    const int b = blockIdx.x, t = threadIdx.x;
    const int base = b * 1024 + t * 4;
    int v0 = (base + 0 < N) ? cnt[base + 0] : 0;
    int v1 = (base + 1 < N) ? cnt[base + 1] : 0;
    int v2 = (base + 2 < N) ? cnt[base + 2] : 0;
    int v3 = (base + 3 < N) ? cnt[base + 3] : 0;
    const int s = v0 + v1 + v2 + v3;
    sm[t] = s; __syncthreads();
    for (int off = 1; off < 256; off <<= 1) {
        int x = (t >= off) ? sm[t - off] : 0;
        __syncthreads();
        sm[t] += x;
        __syncthreads();
    }
    const int e = sm[t] - s;
    if (t == 255) blocksum[b] = sm[t];
    if (base + 0 < N) excl[base + 0] = e;
    if (base + 1 < N) excl[base + 1] = e + v0;
    if (base + 2 < N) excl[base + 2] = e + v0 + v1;
    if (base + 3 < N) excl[base + 3] = e + v0 + v1 + v2;
}

// CSR build 2b: scan block sums (nb <= 256), write grand total at offsets[N].
__global__ __launch_bounds__(256)
void scanB(const int* __restrict__ blocksum, int* __restrict__ blockbase,
           int nb, int* __restrict__ total_out) {
    __shared__ int sm[256];
    const int t = threadIdx.x;
    const int s = (t < nb) ? blocksum[t] : 0;
    sm[t] = s; __syncthreads();
    for (int off = 1; off < 256; off <<= 1) {
        int x = (t >= off) ? sm[t - off] : 0;
        __syncthreads();
        sm[t] += x;
        __syncthreads();
    }
    if (t < nb) blockbase[t] = sm[t] - s;
    if (t == 255) *total_out = sm[255];
}

// CSR build 2c: add block bases; duplicate into ofs_work (consumed by
// phase1's embedded fill atomics).
__global__ __launch_bounds__(256)
void scanC(int* __restrict__ offsets, int* __restrict__ ofs_work,
           const int* __restrict__ blockbase, int N) {
    int i = blockIdx.x * 256 + threadIdx.x;
    if (i >= N) return;
    const int v = offsets[i] + blockbase[i >> 10];
    offsets[i]  = v;
    ofs_work[i] = v;
}

// ---------------------------------------------------------------------------
// Phase 1: implicit-GEMM (MFMA) with EMBEDDED CSR fill: quad-0 lanes claim
// the pair's CSR slot via an L2-resident atomic (replaces the fill_kernel
// dispatch and the 10.8 MB slot-array round-trip). Partial row (128 B fp16)
// written at its CSR slot; phase 2 reads contiguously.
// ---------------------------------------------------------------------------
__global__ __launch_bounds__(256)
void spconv_phase1(const unsigned short* __restrict__ featsb,
                   const float*          __restrict__ weight,
                   const int*            __restrict__ in_map,
                   const int*            __restrict__ out_map,
                   int*                  __restrict__ ofs_work,
                   unsigned*             __restrict__ partial_dw,
                   int M) {
    const int k      = blockIdx.y;
    const int tid    = threadIdx.x;
    const int lane   = tid & 63;
    const int m      = lane & 15;
    const int quad   = lane >> 4;
    const int wave   = blockIdx.x * 4 + (tid >> 6);
    const int nwaves = gridDim.x * 4;
    const bool odd   = (m & 1);

    // Preload B fragments: b[t][h][j] = W[k][32h+8q+j][16t+m]
    const float* __restrict__ wk = weight + (size_t)k * (CIN * COUT);
    bf16x8 bfrag[4][2];
#pragma unroll
    for (int t = 0; t < 4; ++t)
#pragma unroll
        for (int h = 0; h < 2; ++h) {
            const int n  = 16 * t + m;
            const int c0 = 32 * h + 8 * quad;
#pragma unroll
            for (int j = 0; j < 8; ++j)
                bfrag[t][h][j] = (short)f2bf(wk[(c0 + j) * COUT + n]);
        }

    const int base   = k * M;
    const int ntiles = M >> 4;   // 3125

    for (int tile = wave; tile < ntiles; tile += nwaves) {
        const int p0      = tile << 4;
        const int in_row  = in_map[base + p0 + m];
        const int out_row = out_map[base + p0 + m];

        // Embedded fill: one atomic per pair (quad-0 lanes only; lanes 0..15
        // then hold the CSR slot of pair m, sourced below via shfl).
        int slt = 0;
        if (quad == 0)
            slt = atomicAdd(&ofs_work[out_row], 1);

        const unsigned short* fb = featsb + ((size_t)in_row << 6) + 8 * quad;
        const bf16x8 a0 = *(const bf16x8*)fb;          // channels [8q, 8q+8)
        const bf16x8 a1 = *(const bf16x8*)(fb + 32);   // channels [8q+32, 8q+40)

        f32x4 acc[4];
#pragma unroll
        for (int t = 0; t < 4; ++t) {
            acc[t] = {0.f, 0.f, 0.f, 0.f};
            acc[t] = __builtin_amdgcn_mfma_f32_16x16x32_bf16(a0, bfrag[t][0], acc[t], 0, 0, 0);
            acc[t] = __builtin_amdgcn_mfma_f32_16x16x32_bf16(a1, bfrag[t][1], acc[t], 0, 0, 0);
        }

        // Epilogue: pair cols (m, m^1) via shfl_xor(1); even lane writes
        // C-rows 4q+{0,1}, odd lane 4q+{2,3}; dword half2 stores into the
        // destination rows' CSR slots.
        const int row0  = 4 * quad + (odd ? 2 : 0);
        const int s0    = __shfl(slt, row0);       // lane row0 (quad 0) holds it
        const int s1    = __shfl(slt, row0 + 1);
        const int coldw = m >> 1;
#pragma unroll
        for (int t = 0; t < 4; ++t) {
            const float send0 = odd ? acc[t][0] : acc[t][2];
            const float send1 = odd ? acc[t][1] : acc[t][3];
            const float recv0 = __shfl_xor(send0, 1);
            const float recv1 = __shfl_xor(send1, 1);

            const unsigned d0 = odd ? pack_h2(recv0, acc[t][2])
                                    : pack_h2(acc[t][0], recv0);
            const unsigned d1 = odd ? pack_h2(recv1, acc[t][3])
                                    : pack_h2(acc[t][1], recv1);

            partial_dw[(size_t)s0 * 32 + coldw + 8 * t] = d0;
            partial_dw[(size_t)s1 * 32 + coldw + 8 * t] = d1;
        }
    }
}

// ---------------------------------------------------------------------------
// Phase 2: streaming CSR reduce. One wave per out row; contributions are
// contiguous. Lane reads a dword (2 cols); 32 lanes cover one 128 B entry;
// 2 entries/step, 4 loads in flight. Next row's offsets prefetched.
// ---------------------------------------------------------------------------
__global__ __launch_bounds__(256)
void spconv_phase2(const unsigned* __restrict__ partial_dw,
                   const int*      __restrict__ offsets,
                   float2*         __restrict__ out,
                   int nrows) {
    const int tid  = threadIdx.x;
    const int lane = tid & 63;
    const int half = lane >> 5;
    const int c2   = lane & 31;
    const int wave = blockIdx.x * 4 + (tid >> 6);
    const int nw   = gridDim.x * 4;

    if (wave >= nrows) return;
    int cur_s = offsets[wave];
    int cur_e = offsets[wave + 1];

    for (int r = wave; r < nrows; r += nw) {
        const int start = cur_s;
        const int c     = cur_e - start;
        const int rn    = r + nw;
        if (rn < nrows) {                 // prefetch next row's extent
            cur_s = offsets[rn];
            cur_e = offsets[rn + 1];
        }

        float ax = 0.f, ay = 0.f;
        for (int j0 = 0; j0 < c; j0 += 8) {
#pragma unroll
            for (int u = 0; u < 4; ++u) {
                const int j = j0 + 2 * u + half;
                if (j < c) {
                    const unsigned v = partial_dw[(size_t)(start + j) * 32 + c2];
                    ax += __half2float(__ushort_as_half((unsigned short)(v & 0xFFFF)));
                    ay += __half2float(__ushort_as_half((unsigned short)(v >> 16)));
                }
            }
        }

        ax += __shfl_xor(ax, 32);
        ay += __shfl_xor(ay, 32);
        if (half == 0)
            out[(size_t)r * 32 + c2] = make_float2(ax, ay);
    }
}

// ---------------------------------------------------------------------------
// Fallback (ws too small): round-2 kernel — scalar f32 atomics (known-good).
// ---------------------------------------------------------------------------
__global__ __launch_bounds__(256)
void spconv_atomic(const float* __restrict__ feats,
                   const float* __restrict__ weight,
                   const int*   __restrict__ in_map,
                   const int*   __restrict__ out_map,
                   float*       __restrict__ out,
                   int M) {
    const int k      = blockIdx.y;
    const int tid    = threadIdx.x;
    const int lane   = tid & 63;
    const int m      = lane & 15;
    const int quad   = lane >> 4;
    const int wave   = blockIdx.x * 4 + (tid >> 6);
    const int nwaves = gridDim.x * 4;

    const float* __restrict__ wk = weight + (size_t)k * (CIN * COUT);
    bf16x8 bfrag[4][2];
#pragma unroll
    for (int t = 0; t < 4; ++t)
#pragma unroll
        for (int h = 0; h < 2; ++h) {
            const int n  = 16 * t + m;
            const int c0 = 32 * h + 8 * quad;
#pragma unroll
            for (int j = 0; j < 8; ++j)
                bfrag[t][h][j] = (short)f2bf(wk[(c0 + j) * COUT + n]);
        }

    const int base   = k * M;
    const int ntiles = M >> 4;

    for (int tile = wave; tile < ntiles; tile += nwaves) {
        const int p0 = tile << 4;
        const int in_row  = in_map[base + p0 + m];
        const int out_row = out_map[base + p0 + m];

        const float* __restrict__ fr = feats + ((size_t)in_row << 6) + 8 * quad;
        const f32x4 f0 = *(const f32x4*)(fr + 0);
        const f32x4 f1 = *(const f32x4*)(fr + 4);
        const f32x4 f2 = *(const f32x4*)(fr + 32);
        const f32x4 f3 = *(const f32x4*)(fr + 36);

        bf16x8 a0, a1;
#pragma unroll
        for (int j = 0; j < 4; ++j) {
            a0[j]     = (short)f2bf(f0[j]);
            a0[j + 4] = (short)f2bf(f1[j]);
            a1[j]     = (short)f2bf(f2[j]);
            a1[j + 4] = (short)f2bf(f3[j]);
        }

        int orow[4];
#pragma unroll
        for (int r = 0; r < 4; ++r)
            orow[r] = __shfl(out_row, 4 * quad + r);

        f32x4 acc[4];
#pragma unroll
        for (int t = 0; t < 4; ++t) {
            acc[t] = {0.f, 0.f, 0.f, 0.f};
            acc[t] = __builtin_amdgcn_mfma_f32_16x16x32_bf16(a0, bfrag[t][0], acc[t], 0, 0, 0);
            acc[t] = __builtin_amdgcn_mfma_f32_16x16x32_bf16(a1, bfrag[t][1], acc[t], 0, 0, 0);
        }

#pragma unroll
        for (int t = 0; t < 4; ++t)
#pragma unroll
            for (int r = 0; r < 4; ++r)
                atomicAdd(out + (size_t)orow[r] * COUT + 16 * t + m, acc[t][r]);
    }
}

__global__ __launch_bounds__(256)
void zero_out_kernel(float4* __restrict__ out, int n4) {
    int i = blockIdx.x * 256 + threadIdx.x;
    if (i < n4) out[i] = make_float4(0.f, 0.f, 0.f, 0.f);
}

static inline size_t al256(size_t x) { return (x + 255) & ~(size_t)255; }

extern "C" void kernel_launch(void* const* d_in, const int* in_sizes, int n_in,
                              void* d_out, int out_size, void* d_ws, size_t ws_size,
                              hipStream_t stream) {
    const float* feats   = (const float*)d_in[0];
    const float* weight  = (const float*)d_in[1];
    const int*   in_map  = (const int*)d_in[2];
    const int*   out_map = (const int*)d_in[3];
    float*       out     = (float*)d_out;

    const int K     = in_sizes[1] / (CIN * COUT);   // 27
    const int M     = in_sizes[2] / K;              // 50000
    const int N     = out_size / COUT;              // 200000
    const int total = K * M;                        // 1.35M
    const int nb    = (N + 1023) >> 10;             // scan blocks (196)

    // ws layout: offsets[N+1] | ofs_work[N] | blocksum[nb] | blockbase[nb]
    //            | featsb bf16[N*CIN] | partial fp16[total*64]
    const size_t off_b  = al256((size_t)(N + 1) * 4);
    const size_t work_b = al256((size_t)N * 4);
    const size_t bs_b   = al256((size_t)nb * 4);
    const size_t bb_b   = al256((size_t)nb * 4);
    const size_t fb_b   = al256((size_t)N * CIN * 2);
    const size_t part_b = (size_t)total * COUT * 2;
    const size_t need   = off_b + work_b + bs_b + bb_b + fb_b + part_b;

    if ((M & 15) == 0 && nb <= 256 && ws_size >= need) {
        char* p = (char*)d_ws;
        int*            offsets   = (int*)p;            p += off_b;
        int*            ofs_work  = (int*)p;            p += work_b;
        int*            blocksum  = (int*)p;            p += bs_b;
        int*            blockbase = (int*)p;            p += bb_b;
        unsigned short* featsb    = (unsigned short*)p; p += fb_b;
        unsigned*       partial   = (unsigned*)p;

        const int n8 = N * CIN / 8;
        const int fused_n = (n8 > total) ? n8 : total;

        hipMemsetAsync(ofs_work, 0, (size_t)N * 4, stream);
        cvt_hist<<<(fused_n + 255) / 256, 256, 0, stream>>>(
            (const float4*)feats, featsb, n8, out_map, total, ofs_work);
        scanA<<<nb, 256, 0, stream>>>(ofs_work, offsets, blocksum, N);
        scanB<<<1, 256, 0, stream>>>(blocksum, blockbase, nb, offsets + N);
        scanC<<<(N + 255) / 256, 256, 0, stream>>>(offsets, ofs_work, blockbase, N);

        dim3 g1(80, K);
        spconv_phase1<<<g1, 256, 0, stream>>>(featsb, weight, in_map, out_map,
                                              ofs_work, partial, M);

        spconv_phase2<<<8192, 256, 0, stream>>>(partial, offsets, (float2*)out, N);
        return;
    }

    // Fallback: known-good scalar-atomic path.
    int n4 = out_size / 4;
    zero_out_kernel<<<(n4 + 255) / 256, 256, 0, stream>>>((float4*)out, n4);
    dim3 grid(80, K);
    spconv_atomic<<<grid, 256, 0, stream>>>(feats, weight, in_map, out_map, out, M);
}

// Round 10
// 322.456 us; speedup vs baseline: 1.2270x; 1.0289x over previous
//
#include <hip/hip_runtime.h>
#include <hip/hip_fp16.h>

#define CIN   64
#define COUT  64

typedef __attribute__((ext_vector_type(8))) short bf16x8;
typedef __attribute__((ext_vector_type(4))) float f32x4;

// round-to-nearest-even f32 -> bf16 (bit pattern as ushort)
__device__ inline unsigned short f2bf(float f) {
    unsigned u = __float_as_uint(f);
    return (unsigned short)((u + 0x7FFFu + ((u >> 16) & 1u)) >> 16);
}

__device__ inline unsigned pack_h2(float lo, float hi) {
    __half l = __float2half(lo), h = __float2half(hi);
    return (unsigned)__half_as_ushort(l) | ((unsigned)__half_as_ushort(h) << 16);
}

// ---------------------------------------------------------------------------
// Fused: feats fp32 -> bf16 AND out_map histogram (cnt must be pre-zeroed).
// ---------------------------------------------------------------------------
__global__ __launch_bounds__(256)
void cvt_hist(const float4* __restrict__ in, unsigned short* __restrict__ outb,
              int n8, const int* __restrict__ out_map, int total,
              int* __restrict__ cnt) {
    int i = blockIdx.x * 256 + threadIdx.x;
    if (i < n8) {
        float4 f0 = in[2 * i], f1 = in[2 * i + 1];
        bf16x8 o;
        o[0] = (short)f2bf(f0.x); o[1] = (short)f2bf(f0.y);
        o[2] = (short)f2bf(f0.z); o[3] = (short)f2bf(f0.w);
        o[4] = (short)f2bf(f1.x); o[5] = (short)f2bf(f1.y);
        o[6] = (short)f2bf(f1.z); o[7] = (short)f2bf(f1.w);
        *(bf16x8*)(outb + 8 * (size_t)i) = o;
    }
    if (i < total)
        atomicAdd(&cnt[out_map[i]], 1);
}

// CSR build 2a: per-block (1024 elems) exclusive scan + block sums.
__global__ __launch_bounds__(256)
void scanA(const int* __restrict__ cnt, int* __restrict__ excl,
           int* __restrict__ blocksum, int N) {
    __shared__ int sm[256];
    const int b = blockIdx.x, t = threadIdx.x;
    const int base = b * 1024 + t * 4;
    int v0 = (base + 0 < N) ? cnt[base + 0] : 0;
    int v1 = (base + 1 < N) ? cnt[base + 1] : 0;
    int v2 = (base + 2 < N) ? cnt[base + 2] : 0;
    int v3 = (base + 3 < N) ? cnt[base + 3] : 0;
    const int s = v0 + v1 + v2 + v3;
    sm[t] = s; __syncthreads();
    for (int off = 1; off < 256; off <<= 1) {
        int x = (t >= off) ? sm[t - off] : 0;
        __syncthreads();
        sm[t] += x;
        __syncthreads();
    }
    const int e = sm[t] - s;
    if (t == 255) blocksum[b] = sm[t];
    if (base + 0 < N) excl[base + 0] = e;
    if (base + 1 < N) excl[base + 1] = e + v0;
    if (base + 2 < N) excl[base + 2] = e + v0 + v1;
    if (base + 3 < N) excl[base + 3] = e + v0 + v1 + v2;
}

// CSR build 2b: scan block sums (nb <= 256), write grand total at offsets[N].
__global__ __launch_bounds__(256)
void scanB(const int* __restrict__ blocksum, int* __restrict__ blockbase,
           int nb, int* __restrict__ total_out) {
    __shared__ int sm[256];
    const int t = threadIdx.x;
    const int s = (t < nb) ? blocksum[t] : 0;
    sm[t] = s; __syncthreads();
    for (int off = 1; off < 256; off <<= 1) {
        int x = (t >= off) ? sm[t - off] : 0;
        __syncthreads();
        sm[t] += x;
        __syncthreads();
    }
    if (t < nb) blockbase[t] = sm[t] - s;
    if (t == 255) *total_out = sm[255];
}

// CSR build 2c: add block bases; duplicate into ofs_work (consumed by
// phase1's embedded fill atomics).
__global__ __launch_bounds__(256)
void scanC(int* __restrict__ offsets, int* __restrict__ ofs_work,
           const int* __restrict__ blockbase, int N) {
    int i = blockIdx.x * 256 + threadIdx.x;
    if (i >= N) return;
    const int v = offsets[i] + blockbase[i >> 10];
    offsets[i]  = v;
    ofs_work[i] = v;
}

// ---------------------------------------------------------------------------
// Phase 1: implicit-GEMM (MFMA), embedded CSR fill, SOFTWARE-PIPELINED:
// next tile's indices + slot-atomic + feats gather issue BEFORE the current
// tile's MFMA/stores, hiding the ~900-cycle atomic/gather latency (round-9
// lesson: unpipelined embedded atomic put that latency on the critical path).
// ---------------------------------------------------------------------------
__global__ __launch_bounds__(256)
void spconv_phase1(const unsigned short* __restrict__ featsb,
                   const float*          __restrict__ weight,
                   const int*            __restrict__ in_map,
                   const int*            __restrict__ out_map,
                   int*                  __restrict__ ofs_work,
                   unsigned*             __restrict__ partial_dw,
                   int M) {
    const int k      = blockIdx.y;
    const int tid    = threadIdx.x;
    const int lane   = tid & 63;
    const int m      = lane & 15;
    const int quad   = lane >> 4;
    const int wave   = blockIdx.x * 4 + (tid >> 6);
    const int nwaves = gridDim.x * 4;
    const bool odd   = (m & 1);

    // Preload B fragments: b[t][h][j] = W[k][32h+8q+j][16t+m]
    const float* __restrict__ wk = weight + (size_t)k * (CIN * COUT);
    bf16x8 bfrag[4][2];
#pragma unroll
    for (int t = 0; t < 4; ++t)
#pragma unroll
        for (int h = 0; h < 2; ++h) {
            const int n  = 16 * t + m;
            const int c0 = 32 * h + 8 * quad;
#pragma unroll
            for (int j = 0; j < 8; ++j)
                bfrag[t][h][j] = (short)f2bf(wk[(c0 + j) * COUT + n]);
        }

    const int base   = k * M;
    const int ntiles = M >> 4;   // 3125

    // ---- pipeline prologue: tile0's indices, slot atomic, feats gather ----
    int    tile = wave;
    int    cur_slt = 0;
    bf16x8 cur_a0 = {}, cur_a1 = {};
    if (tile < ntiles) {
        const int p0 = tile << 4;
        const int in_row  = in_map[base + p0 + m];
        const int out_row = out_map[base + p0 + m];
        if (quad == 0) cur_slt = atomicAdd(&ofs_work[out_row], 1);
        const unsigned short* fb = featsb + ((size_t)in_row << 6) + 8 * quad;
        cur_a0 = *(const bf16x8*)fb;
        cur_a1 = *(const bf16x8*)(fb + 32);
    }

    while (tile < ntiles) {
        // ---- prefetch next tile (independent of current compute) ----
        const int next = tile + nwaves;
        int    nxt_slt = 0;
        bf16x8 nxt_a0 = {}, nxt_a1 = {};
        if (next < ntiles) {
            const int np0 = next << 4;
            const int n_in  = in_map[base + np0 + m];
            const int n_out = out_map[base + np0 + m];
            if (quad == 0) nxt_slt = atomicAdd(&ofs_work[n_out], 1);
            const unsigned short* fb = featsb + ((size_t)n_in << 6) + 8 * quad;
            nxt_a0 = *(const bf16x8*)fb;
            nxt_a1 = *(const bf16x8*)(fb + 32);
        }

        // ---- compute current tile ----
        f32x4 acc[4];
#pragma unroll
        for (int t = 0; t < 4; ++t) {
            acc[t] = {0.f, 0.f, 0.f, 0.f};
            acc[t] = __builtin_amdgcn_mfma_f32_16x16x32_bf16(cur_a0, bfrag[t][0], acc[t], 0, 0, 0);
            acc[t] = __builtin_amdgcn_mfma_f32_16x16x32_bf16(cur_a1, bfrag[t][1], acc[t], 0, 0, 0);
        }

        // Epilogue: pair cols (m, m^1) via shfl_xor(1); even lane writes
        // C-rows 4q+{0,1}, odd lane 4q+{2,3}; dword half2 stores at CSR slots.
        const int row0  = 4 * quad + (odd ? 2 : 0);
        const int s0    = __shfl(cur_slt, row0);     // quad-0 lane row0 holds it
        const int s1    = __shfl(cur_slt, row0 + 1);
        const int coldw = m >> 1;
#pragma unroll
        for (int t = 0; t < 4; ++t) {
            const float send0 = odd ? acc[t][0] : acc[t][2];
            const float send1 = odd ? acc[t][1] : acc[t][3];
            const float recv0 = __shfl_xor(send0, 1);
            const float recv1 = __shfl_xor(send1, 1);

            const unsigned d0 = odd ? pack_h2(recv0, acc[t][2])
                                    : pack_h2(acc[t][0], recv0);
            const unsigned d1 = odd ? pack_h2(recv1, acc[t][3])
                                    : pack_h2(acc[t][1], recv1);

            partial_dw[(size_t)s0 * 32 + coldw + 8 * t] = d0;
            partial_dw[(size_t)s1 * 32 + coldw + 8 * t] = d1;
        }

        // ---- rotate pipeline ----
        tile    = next;
        cur_slt = nxt_slt;
        cur_a0  = nxt_a0;
        cur_a1  = nxt_a1;
    }
}

// ---------------------------------------------------------------------------
// Phase 2: streaming CSR reduce. One wave per out row; contributions are
// contiguous. Lane reads a dword (2 cols); 32 lanes cover one 128 B entry;
// 2 entries/step, 4 loads in flight. Next row's offsets prefetched.
// ---------------------------------------------------------------------------
__global__ __launch_bounds__(256)
void spconv_phase2(const unsigned* __restrict__ partial_dw,
                   const int*      __restrict__ offsets,
                   float2*         __restrict__ out,
                   int nrows) {
    const int tid  = threadIdx.x;
    const int lane = tid & 63;
    const int half = lane >> 5;
    const int c2   = lane & 31;
    const int wave = blockIdx.x * 4 + (tid >> 6);
    const int nw   = gridDim.x * 4;

    if (wave >= nrows) return;
    int cur_s = offsets[wave];
    int cur_e = offsets[wave + 1];

    for (int r = wave; r < nrows; r += nw) {
        const int start = cur_s;
        const int c     = cur_e - start;
        const int rn    = r + nw;
        if (rn < nrows) {                 // prefetch next row's extent
            cur_s = offsets[rn];
            cur_e = offsets[rn + 1];
        }

        float ax = 0.f, ay = 0.f;
        for (int j0 = 0; j0 < c; j0 += 8) {
#pragma unroll
            for (int u = 0; u < 4; ++u) {
                const int j = j0 + 2 * u + half;
                if (j < c) {
                    const unsigned v = partial_dw[(size_t)(start + j) * 32 + c2];
                    ax += __half2float(__ushort_as_half((unsigned short)(v & 0xFFFF)));
                    ay += __half2float(__ushort_as_half((unsigned short)(v >> 16)));
                }
            }
        }

        ax += __shfl_xor(ax, 32);
        ay += __shfl_xor(ay, 32);
        if (half == 0)
            out[(size_t)r * 32 + c2] = make_float2(ax, ay);
    }
}

// ---------------------------------------------------------------------------
// Fallback (ws too small): round-2 kernel — scalar f32 atomics (known-good).
// ---------------------------------------------------------------------------
__global__ __launch_bounds__(256)
void spconv_atomic(const float* __restrict__ feats,
                   const float* __restrict__ weight,
                   const int*   __restrict__ in_map,
                   const int*   __restrict__ out_map,
                   float*       __restrict__ out,
                   int M) {
    const int k      = blockIdx.y;
    const int tid    = threadIdx.x;
    const int lane   = tid & 63;
    const int m      = lane & 15;
    const int quad   = lane >> 4;
    const int wave   = blockIdx.x * 4 + (tid >> 6);
    const int nwaves = gridDim.x * 4;

    const float* __restrict__ wk = weight + (size_t)k * (CIN * COUT);
    bf16x8 bfrag[4][2];
#pragma unroll
    for (int t = 0; t < 4; ++t)
#pragma unroll
        for (int h = 0; h < 2; ++h) {
            const int n  = 16 * t + m;
            const int c0 = 32 * h + 8 * quad;
#pragma unroll
            for (int j = 0; j < 8; ++j)
                bfrag[t][h][j] = (short)f2bf(wk[(c0 + j) * COUT + n]);
        }

    const int base   = k * M;
    const int ntiles = M >> 4;

    for (int tile = wave; tile < ntiles; tile += nwaves) {
        const int p0 = tile << 4;
        const int in_row  = in_map[base + p0 + m];
        const int out_row = out_map[base + p0 + m];

        const float* __restrict__ fr = feats + ((size_t)in_row << 6) + 8 * quad;
        const f32x4 f0 = *(const f32x4*)(fr + 0);
        const f32x4 f1 = *(const f32x4*)(fr + 4);
        const f32x4 f2 = *(const f32x4*)(fr + 32);
        const f32x4 f3 = *(const f32x4*)(fr + 36);

        bf16x8 a0, a1;
#pragma unroll
        for (int j = 0; j < 4; ++j) {
            a0[j]     = (short)f2bf(f0[j]);
            a0[j + 4] = (short)f2bf(f1[j]);
            a1[j]     = (short)f2bf(f2[j]);
            a1[j + 4] = (short)f2bf(f3[j]);
        }

        int orow[4];
#pragma unroll
        for (int r = 0; r < 4; ++r)
            orow[r] = __shfl(out_row, 4 * quad + r);

        f32x4 acc[4];
#pragma unroll
        for (int t = 0; t < 4; ++t) {
            acc[t] = {0.f, 0.f, 0.f, 0.f};
            acc[t] = __builtin_amdgcn_mfma_f32_16x16x32_bf16(a0, bfrag[t][0], acc[t], 0, 0, 0);
            acc[t] = __builtin_amdgcn_mfma_f32_16x16x32_bf16(a1, bfrag[t][1], acc[t], 0, 0, 0);
        }

#pragma unroll
        for (int t = 0; t < 4; ++t)
#pragma unroll
            for (int r = 0; r < 4; ++r)
                atomicAdd(out + (size_t)orow[r] * COUT + 16 * t + m, acc[t][r]);
    }
}

__global__ __launch_bounds__(256)
void zero_out_kernel(float4* __restrict__ out, int n4) {
    int i = blockIdx.x * 256 + threadIdx.x;
    if (i < n4) out[i] = make_float4(0.f, 0.f, 0.f, 0.f);
}

static inline size_t al256(size_t x) { return (x + 255) & ~(size_t)255; }

extern "C" void kernel_launch(void* const* d_in, const int* in_sizes, int n_in,
                              void* d_out, int out_size, void* d_ws, size_t ws_size,
                              hipStream_t stream) {
    const float* feats   = (const float*)d_in[0];
    const float* weight  = (const float*)d_in[1];
    const int*   in_map  = (const int*)d_in[2];
    const int*   out_map = (const int*)d_in[3];
    float*       out     = (float*)d_out;

    const int K     = in_sizes[1] / (CIN * COUT);   // 27
    const int M     = in_sizes[2] / K;              // 50000
    const int N     = out_size / COUT;              // 200000
    const int total = K * M;                        // 1.35M
    const int nb    = (N + 1023) >> 10;             // scan blocks (196)

    // ws layout: offsets[N+1] | ofs_work[N] | blocksum[nb] | blockbase[nb]
    //            | featsb bf16[N*CIN] | partial fp16[total*64]
    const size_t off_b  = al256((size_t)(N + 1) * 4);
    const size_t work_b = al256((size_t)N * 4);
    const size_t bs_b   = al256((size_t)nb * 4);
    const size_t bb_b   = al256((size_t)nb * 4);
    const size_t fb_b   = al256((size_t)N * CIN * 2);
    const size_t part_b = (size_t)total * COUT * 2;
    const size_t need   = off_b + work_b + bs_b + bb_b + fb_b + part_b;

    if ((M & 15) == 0 && nb <= 256 && ws_size >= need) {
        char* p = (char*)d_ws;
        int*            offsets   = (int*)p;            p += off_b;
        int*            ofs_work  = (int*)p;            p += work_b;
        int*            blocksum  = (int*)p;            p += bs_b;
        int*            blockbase = (int*)p;            p += bb_b;
        unsigned short* featsb    = (unsigned short*)p; p += fb_b;
        unsigned*       partial   = (unsigned*)p;

        const int n8 = N * CIN / 8;
        const int fused_n = (n8 > total) ? n8 : total;

        hipMemsetAsync(ofs_work, 0, (size_t)N * 4, stream);
        cvt_hist<<<(fused_n + 255) / 256, 256, 0, stream>>>(
            (const float4*)feats, featsb, n8, out_map, total, ofs_work);
        scanA<<<nb, 256, 0, stream>>>(ofs_work, offsets, blocksum, N);
        scanB<<<1, 256, 0, stream>>>(blocksum, blockbase, nb, offsets + N);
        scanC<<<(N + 255) / 256, 256, 0, stream>>>(offsets, ofs_work, blockbase, N);

        dim3 g1(80, K);
        spconv_phase1<<<g1, 256, 0, stream>>>(featsb, weight, in_map, out_map,
                                              ofs_work, partial, M);

        spconv_phase2<<<8192, 256, 0, stream>>>(partial, offsets, (float2*)out, N);
        return;
    }

    // Fallback: known-good scalar-atomic path.
    int n4 = out_size / 4;
    zero_out_kernel<<<(n4 + 255) / 256, 256, 0, stream>>>((float4*)out, n4);
    dim3 grid(80, K);
    spconv_atomic<<<grid, 256, 0, stream>>>(feats, weight, in_map, out_map, out, M);
}